// Round 1
// baseline (518.024 us; speedup 1.0000x reference)
//
#include <hip/hip_runtime.h>
#include <hip/hip_bf16.h>

// Problem constants (fixed by setup_inputs)
#define B_    8
#define H_    8
#define DH_   64
#define FR    16
#define SP    196
#define NTOK  3137            // 1 + FR*SP
#define DIM   512
#define NQKV  1536
#define MREAL (B_ * NTOK)     // 25096
#define MPAD  25216           // 197 * 128

typedef __bf16 bf16x8 __attribute__((ext_vector_type(8)));
typedef float  f32x4  __attribute__((ext_vector_type(4)));
typedef unsigned short ushort8 __attribute__((ext_vector_type(8)));

__device__ __forceinline__ float bf2f(unsigned short u) {
    union { unsigned int i; float f; } x; x.i = ((unsigned int)u) << 16; return x.f;
}
__device__ __forceinline__ unsigned short f2bf(float f) {
    __hip_bfloat16 h = __float2bfloat16(f);
    union { __hip_bfloat16 h; unsigned short u; } x; x.h = h; return x.u;
}

// ---------------- prep kernels ----------------

// x (fp32, MREAL x 512) -> bf16 padded to MPAD rows (pad rows zero)
__global__ __launch_bounds__(256) void convert_pad_x(const float* __restrict__ x,
                                                     unsigned short* __restrict__ xb) {
    int idx = blockIdx.x * 256 + threadIdx.x;          // one 8-elem chunk each
    const int real8 = MREAL * DIM / 8;
    ushort8 o;
    if (idx < real8) {
        f32x4 a = *(const f32x4*)(x + (size_t)idx * 8);
        f32x4 b = *(const f32x4*)(x + (size_t)idx * 8 + 4);
        o[0] = f2bf(a[0]); o[1] = f2bf(a[1]); o[2] = f2bf(a[2]); o[3] = f2bf(a[3]);
        o[4] = f2bf(b[0]); o[5] = f2bf(b[1]); o[6] = f2bf(b[2]); o[7] = f2bf(b[3]);
    } else {
        o = (ushort8){0,0,0,0,0,0,0,0};
    }
    *(ushort8*)(xb + (size_t)idx * 8) = o;
}

// W (fp32, K x Nn) -> WT (bf16, Nn x K)   (B^T layout for the GEMM)
__global__ __launch_bounds__(256) void transpose_w(const float* __restrict__ W,
                                                   unsigned short* __restrict__ WT,
                                                   int K, int Nn) {
    __shared__ float tile[32][33];
    int n0 = blockIdx.x * 32, k0 = blockIdx.y * 32;
    int tx = threadIdx.x & 31, ty = threadIdx.x >> 5;   // ty 0..7
#pragma unroll
    for (int r = 0; r < 32; r += 8)
        tile[ty + r][tx] = W[(size_t)(k0 + ty + r) * Nn + n0 + tx];
    __syncthreads();
#pragma unroll
    for (int r = 0; r < 32; r += 8)
        WT[(size_t)(n0 + ty + r) * K + k0 + tx] = f2bf(tile[tx][ty + r]);
}

// zero the pad rows of the attention-output buffer (poisoned 0xAA each launch)
__global__ __launch_bounds__(256) void zero_pad_attn(unsigned short* __restrict__ attn) {
    int idx = blockIdx.x * 256 + threadIdx.x;           // (MPAD-MREAL)*512/8 chunks
    ushort8 z = (ushort8){0,0,0,0,0,0,0,0};
    *(ushort8*)(attn + (size_t)MREAL * DIM + (size_t)idx * 8) = z;
}

// ---------------- bf16 MFMA GEMM (m97 structure: 128x128 tile, BK=32) ----------------

__device__ __forceinline__ void gload_lds16(const unsigned short* g, unsigned short* l) {
    __builtin_amdgcn_global_load_lds((const __attribute__((address_space(1))) void*)g,
                                     (__attribute__((address_space(3))) void*)l, 16, 0, 0);
}

// EPI 0: bf16 out, scale cols<DIM by 0.125 (q-scale).  EPI 1: fp32 out + bias, rows<MREAL.
template<int EPI>
__global__ __launch_bounds__(256)
void gemm_bt(const unsigned short* __restrict__ A, const unsigned short* __restrict__ Bt,
             unsigned short* __restrict__ Cb, float* __restrict__ Cf,
             const float* __restrict__ bias, int Nn, int K) {
    __shared__ __attribute__((aligned(16))) unsigned short As[128 * 32];
    __shared__ __attribute__((aligned(16))) unsigned short Bs[128 * 32];
    int wave = threadIdx.x >> 6, lane = threadIdx.x & 63;
    int wm = wave >> 1, wn = wave & 1;                 // 2x2 waves, 64x64 each
    int tM = blockIdx.x, tN = blockIdx.y;
    const int r15 = lane & 15, kq = (lane >> 4) * 8;
    f32x4 acc[4][4] = {};

    for (int k0 = 0; k0 < K; k0 += 32) {
#pragma unroll
        for (int r = 0; r < 2; ++r) {
            int chunk = (r * 4 + wave) * 64;           // wave-uniform base chunk
            int ce = chunk + lane;
            int row = ce >> 2, kp = (ce & 3) * 8;
            gload_lds16(A  + (size_t)(tM * 128 + row) * K + k0 + kp, As + chunk * 8);
            gload_lds16(Bt + (size_t)(tN * 128 + row) * K + k0 + kp, Bs + chunk * 8);
        }
        __syncthreads();
        bf16x8 af[4], bg[4];
#pragma unroll
        for (int m = 0; m < 4; m++)
            af[m] = *(const bf16x8*)&As[(wm * 64 + m * 16 + r15) * 32 + kq];
#pragma unroll
        for (int nn = 0; nn < 4; nn++)
            bg[nn] = *(const bf16x8*)&Bs[(wn * 64 + nn * 16 + r15) * 32 + kq];
#pragma unroll
        for (int m = 0; m < 4; m++)
#pragma unroll
            for (int nn = 0; nn < 4; nn++)
                acc[m][nn] = __builtin_amdgcn_mfma_f32_16x16x32_bf16(af[m], bg[nn], acc[m][nn], 0, 0, 0);
        __syncthreads();
    }

    int rowBase = tM * 128 + wm * 64 + (lane >> 4) * 4;
    int colBase = tN * 128 + wn * 64 + r15;
#pragma unroll
    for (int m = 0; m < 4; m++) {
#pragma unroll
        for (int nn = 0; nn < 4; nn++) {
            int col = colBase + nn * 16;
#pragma unroll
            for (int i = 0; i < 4; i++) {
                int row = rowBase + m * 16 + i;
                float v = acc[m][nn][i];
                if constexpr (EPI == 0) {
                    if (col < DIM) v *= 0.125f;        // q scale = DH^-0.5
                    Cb[(size_t)row * Nn + col] = f2bf(v);
                } else {
                    if (row < MREAL) Cf[(size_t)row * Nn + col] = v + bias[col];
                }
            }
        }
    }
}

// ---------------- attention kernels (fp32 math on bf16 qkv) ----------------

// qkv layout: [(b*NTOK + t) * 1536 + sect*512 + h*64 + d], q already scaled.
// CLS: 1 query over all NTOK keys. One block per (b,h).
__global__ __launch_bounds__(256) void cls_attn(const unsigned short* __restrict__ qkv,
                                                unsigned short* __restrict__ attn) {
    int bh = blockIdx.x, b = bh >> 3, h = bh & 7;
    int tid = threadIdx.x;
    __shared__ float sim[NTOK];
    __shared__ float qls[64];
    __shared__ float red[256];
    __shared__ float pv[4][64];
    size_t base = (size_t)b * NTOK * NQKV + h * 64;

    if (tid < 64) qls[tid] = bf2f(qkv[base + tid]);    // q at t=0, sect 0
    __syncthreads();

    float lmax = -1e30f;
    for (int t = tid; t < NTOK; t += 256) {
        const unsigned short* kp = qkv + base + (size_t)t * NQKV + 512;
        float acc = 0.f;
#pragma unroll
        for (int c = 0; c < 8; c++) {
            bf16x8 kv = *(const bf16x8*)(kp + c * 8);
#pragma unroll
            for (int e = 0; e < 8; e++) acc += qls[c * 8 + e] * (float)kv[e];
        }
        sim[t] = acc;
        lmax = fmaxf(lmax, acc);
    }
    red[tid] = lmax; __syncthreads();
    for (int s = 128; s > 0; s >>= 1) {
        if (tid < s) red[tid] = fmaxf(red[tid], red[tid + s]);
        __syncthreads();
    }
    float m = red[0]; __syncthreads();

    float lsum = 0.f;
    for (int t = tid; t < NTOK; t += 256) {
        float p = __expf(sim[t] - m);
        sim[t] = p; lsum += p;
    }
    red[tid] = lsum; __syncthreads();
    for (int s = 128; s > 0; s >>= 1) {
        if (tid < s) red[tid] += red[tid + s];
        __syncthreads();
    }
    float inv = 1.f / red[0]; __syncthreads();

    int wave = tid >> 6, lane = tid & 63;
    float acc = 0.f;
    for (int t = wave; t < NTOK; t += 4)
        acc += sim[t] * bf2f(qkv[base + (size_t)t * NQKV + 1024 + lane]);
    pv[wave][lane] = acc; __syncthreads();
    if (tid < 64) {
        float o = (pv[0][tid] + pv[1][tid] + pv[2][tid] + pv[3][tid]) * inv;
        attn[(size_t)(b * NTOK) * DIM + h * 64 + tid] = f2bf(o);
    }
}

// Time attention: one wave per (b,h,s) sequence: 16 queries over 17 keys (CLS + 16 frames).
__global__ __launch_bounds__(256) void time_attn(const unsigned short* __restrict__ qkv,
                                                 unsigned short* __restrict__ attn) {
    int wave = threadIdx.x >> 6, lane = threadIdx.x & 63;
    int seq = blockIdx.x * 4 + wave;                   // 0 .. B_*H_*SP-1
    int bh = seq / SP, s = seq % SP;
    int b = bh >> 3, h = bh & 7;
    __shared__ __attribute__((aligned(16))) unsigned short Q[4][16][72];
    __shared__ __attribute__((aligned(16))) unsigned short Kt[4][17][72];
    __shared__ __attribute__((aligned(16))) unsigned short Vt[4][17][72];
    __shared__ float S[4][16][18];
    size_t base = (size_t)b * NTOK * NQKV + h * 64;

#pragma unroll
    for (int c = lane; c < 128; c += 64) {             // Q: 16 rows x 8 chunks
        int i = c >> 3, part = c & 7;
        size_t g = base + (size_t)(1 + i * SP + s) * NQKV + part * 8;
        *(ushort8*)&Q[wave][i][part * 8] = *(const ushort8*)(qkv + g);
    }
    for (int c = lane; c < 136; c += 64) {             // K,V: 17 rows x 8 chunks
        int j = c >> 3, part = c & 7;
        int t = (j == 0) ? 0 : (1 + (j - 1) * SP + s);
        size_t g = base + (size_t)t * NQKV + part * 8;
        *(ushort8*)&Kt[wave][j][part * 8] = *(const ushort8*)(qkv + g + 512);
        *(ushort8*)&Vt[wave][j][part * 8] = *(const ushort8*)(qkv + g + 1024);
    }
    __syncthreads();

    for (int p = lane; p < 272; p += 64) {             // S = Q K^T  (16x17)
        int i = p / 17, j = p - i * 17;
        float acc = 0.f;
#pragma unroll
        for (int c = 0; c < 8; c++) {
            bf16x8 qv = *(const bf16x8*)&Q[wave][i][c * 8];
            bf16x8 kv = *(const bf16x8*)&Kt[wave][j][c * 8];
#pragma unroll
            for (int e = 0; e < 8; e++) acc += (float)qv[e] * (float)kv[e];
        }
        S[wave][i][j] = acc;
    }
    __syncthreads();

    if (lane < 16) {                                   // row softmax (17 wide)
        int i = lane;
        float m = -1e30f;
#pragma unroll
        for (int j = 0; j < 17; j++) m = fmaxf(m, S[wave][i][j]);
        float sum = 0.f;
#pragma unroll
        for (int j = 0; j < 17; j++) {
            float p = __expf(S[wave][i][j] - m);
            S[wave][i][j] = p; sum += p;
        }
        float invs = 1.f / sum;
#pragma unroll
        for (int j = 0; j < 17; j++) S[wave][i][j] *= invs;
    }
    __syncthreads();

#pragma unroll
    for (int i = 0; i < 16; i++) {                     // O = P V, lane = dim
        float acc = 0.f;
#pragma unroll
        for (int j = 0; j < 17; j++)
            acc += S[wave][i][j] * bf2f(Vt[wave][j][lane]);
        attn[(size_t)(b * NTOK + 1 + i * SP + s) * DIM + h * 64 + lane] = f2bf(acc);
    }
}

// ---------------- launch ----------------

extern "C" void kernel_launch(void* const* d_in, const int* in_sizes, int n_in,
                              void* d_out, int out_size, void* d_ws, size_t ws_size,
                              hipStream_t stream) {
    (void)in_sizes; (void)n_in; (void)out_size; (void)ws_size;
    const float* x    = (const float*)d_in[0];
    const float* Wqkv = (const float*)d_in[1];
    const float* Wout = (const float*)d_in[2];
    const float* bout = (const float*)d_in[3];
    float* out = (float*)d_out;

    unsigned short* xb    = (unsigned short*)d_ws;                 // MPAD*512
    unsigned short* qkv   = xb    + (size_t)MPAD * DIM;            // MPAD*1536
    unsigned short* attn  = qkv   + (size_t)MPAD * NQKV;           // MPAD*512
    unsigned short* wqkvT = attn  + (size_t)MPAD * DIM;            // 1536*512
    unsigned short* woutT = wqkvT + (size_t)NQKV * DIM;            // 512*512

    convert_pad_x<<<MPAD * DIM / 8 / 256, 256, 0, stream>>>(x, xb);
    transpose_w<<<dim3(NQKV / 32, DIM / 32), 256, 0, stream>>>(Wqkv, wqkvT, DIM, NQKV);
    transpose_w<<<dim3(DIM / 32, DIM / 32), 256, 0, stream>>>(Wout, woutT, DIM, DIM);
    zero_pad_attn<<<(MPAD - MREAL) * DIM / 8 / 256, 256, 0, stream>>>(attn);

    gemm_bt<0><<<dim3(MPAD / 128, NQKV / 128), 256, 0, stream>>>(
        xb, wqkvT, qkv, nullptr, nullptr, NQKV, DIM);

    cls_attn<<<B_ * H_, 256, 0, stream>>>(qkv, attn);
    time_attn<<<(B_ * H_ * SP) / 4, 256, 0, stream>>>(qkv, attn);

    gemm_bt<1><<<dim3(MPAD / 128, DIM / 128), 256, 0, stream>>>(
        attn, woutT, nullptr, out, bout, DIM, DIM);
}

// Round 3
// 315.237 us; speedup vs baseline: 1.6433x; 1.6433x over previous
//
#include <hip/hip_runtime.h>
#include <hip/hip_bf16.h>

// Problem constants (fixed by setup_inputs)
#define B_    8
#define H_    8
#define DH_   64
#define FR    16
#define SP    196
#define NTOK  3137            // 1 + FR*SP
#define DIM   512
#define NQKV  1536
#define MREAL (B_ * NTOK)     // 25096
#define MPAD  25216           // 197 * 128

#define CSPLIT 50             // CLS split-K: 50 chunks of 64 tokens
#define CTOK   64

typedef __bf16 bf16x8 __attribute__((ext_vector_type(8)));
typedef float  f32x4  __attribute__((ext_vector_type(4)));
typedef unsigned short ushort8 __attribute__((ext_vector_type(8)));

__device__ __forceinline__ float bf2f(unsigned short u) {
    union { unsigned int i; float f; } x; x.i = ((unsigned int)u) << 16; return x.f;
}
__device__ __forceinline__ unsigned short f2bf(float f) {
    __hip_bfloat16 h = __float2bfloat16(f);
    union { __hip_bfloat16 h; unsigned short u; } x; x.h = h; return x.u;
}

// ---------------- prep kernels ----------------

// x (fp32, MREAL x 512) -> bf16 padded to MPAD rows (pad rows zero)
__global__ __launch_bounds__(256) void convert_pad_x(const float* __restrict__ x,
                                                     unsigned short* __restrict__ xb) {
    int idx = blockIdx.x * 256 + threadIdx.x;          // one 8-elem chunk each
    const int real8 = MREAL * DIM / 8;
    ushort8 o;
    if (idx < real8) {
        f32x4 a = *(const f32x4*)(x + (size_t)idx * 8);
        f32x4 b = *(const f32x4*)(x + (size_t)idx * 8 + 4);
        o[0] = f2bf(a[0]); o[1] = f2bf(a[1]); o[2] = f2bf(a[2]); o[3] = f2bf(a[3]);
        o[4] = f2bf(b[0]); o[5] = f2bf(b[1]); o[6] = f2bf(b[2]); o[7] = f2bf(b[3]);
    } else {
        o = (ushort8){0,0,0,0,0,0,0,0};
    }
    *(ushort8*)(xb + (size_t)idx * 8) = o;
}

// W (fp32, K x Nn) -> WT (bf16, Nn x K)   (B^T layout for the GEMM)
__global__ __launch_bounds__(256) void transpose_w(const float* __restrict__ W,
                                                   unsigned short* __restrict__ WT,
                                                   int K, int Nn) {
    __shared__ float tile[32][33];
    int n0 = blockIdx.x * 32, k0 = blockIdx.y * 32;
    int tx = threadIdx.x & 31, ty = threadIdx.x >> 5;   // ty 0..7
#pragma unroll
    for (int r = 0; r < 32; r += 8)
        tile[ty + r][tx] = W[(size_t)(k0 + ty + r) * Nn + n0 + tx];
    __syncthreads();
#pragma unroll
    for (int r = 0; r < 32; r += 8)
        WT[(size_t)(n0 + ty + r) * K + k0 + tx] = f2bf(tile[tx][ty + r]);
}

// zero the pad rows of the attention-output buffer (poisoned 0xAA each launch)
__global__ __launch_bounds__(256) void zero_pad_attn(unsigned short* __restrict__ attn) {
    int idx = blockIdx.x * 256 + threadIdx.x;           // (MPAD-MREAL)*512/8 chunks
    ushort8 z = (ushort8){0,0,0,0,0,0,0,0};
    *(ushort8*)(attn + (size_t)MREAL * DIM + (size_t)idx * 8) = z;
}

// ---------------- bf16 MFMA GEMM (m97 structure: 128x128 tile, BK=32) ----------------

__device__ __forceinline__ void gload_lds16(const unsigned short* g, unsigned short* l) {
    __builtin_amdgcn_global_load_lds((const __attribute__((address_space(1))) void*)g,
                                     (__attribute__((address_space(3))) void*)l, 16, 0, 0);
}

// EPI 0: bf16 out, scale cols<DIM by 0.125 (q-scale).  EPI 1: fp32 out + bias, rows<MREAL.
template<int EPI>
__global__ __launch_bounds__(256)
void gemm_bt(const unsigned short* __restrict__ A, const unsigned short* __restrict__ Bt,
             unsigned short* __restrict__ Cb, float* __restrict__ Cf,
             const float* __restrict__ bias, int Nn, int K) {
    __shared__ __attribute__((aligned(16))) unsigned short As[128 * 32];
    __shared__ __attribute__((aligned(16))) unsigned short Bs[128 * 32];
    int wave = threadIdx.x >> 6, lane = threadIdx.x & 63;
    int wm = wave >> 1, wn = wave & 1;                 // 2x2 waves, 64x64 each
    int tM = blockIdx.x, tN = blockIdx.y;
    const int r15 = lane & 15, kq = (lane >> 4) * 8;
    f32x4 acc[4][4] = {};

    for (int k0 = 0; k0 < K; k0 += 32) {
#pragma unroll
        for (int r = 0; r < 2; ++r) {
            int chunk = (r * 4 + wave) * 64;           // wave-uniform base chunk
            int ce = chunk + lane;
            int row = ce >> 2, kp = (ce & 3) * 8;
            gload_lds16(A  + (size_t)(tM * 128 + row) * K + k0 + kp, As + chunk * 8);
            gload_lds16(Bt + (size_t)(tN * 128 + row) * K + k0 + kp, Bs + chunk * 8);
        }
        __syncthreads();
        bf16x8 af[4], bg[4];
#pragma unroll
        for (int m = 0; m < 4; m++)
            af[m] = *(const bf16x8*)&As[(wm * 64 + m * 16 + r15) * 32 + kq];
#pragma unroll
        for (int nn = 0; nn < 4; nn++)
            bg[nn] = *(const bf16x8*)&Bs[(wn * 64 + nn * 16 + r15) * 32 + kq];
#pragma unroll
        for (int m = 0; m < 4; m++)
#pragma unroll
            for (int nn = 0; nn < 4; nn++)
                acc[m][nn] = __builtin_amdgcn_mfma_f32_16x16x32_bf16(af[m], bg[nn], acc[m][nn], 0, 0, 0);
        __syncthreads();
    }

    int rowBase = tM * 128 + wm * 64 + (lane >> 4) * 4;
    int colBase = tN * 128 + wn * 64 + r15;
#pragma unroll
    for (int m = 0; m < 4; m++) {
#pragma unroll
        for (int nn = 0; nn < 4; nn++) {
            int col = colBase + nn * 16;
#pragma unroll
            for (int i = 0; i < 4; i++) {
                int row = rowBase + m * 16 + i;
                float v = acc[m][nn][i];
                if constexpr (EPI == 0) {
                    if (col < DIM) v *= 0.125f;        // q scale = DH^-0.5
                    Cb[(size_t)row * Nn + col] = f2bf(v);
                } else {
                    if (row < MREAL) Cf[(size_t)row * Nn + col] = v + bias[col];
                }
            }
        }
    }
}

// ---------------- CLS attention: flash-style split-K ----------------
// qkv layout: [(b*NTOK + t) * 1536 + sect*512 + h*64 + d], q already scaled.
// Partial: block (split, bh) handles CTOK tokens -> (m, s, pv[64]) unnormalized.
__global__ __launch_bounds__(256) void cls_partial(const unsigned short* __restrict__ qkv,
                                                   float* __restrict__ part) {
    int bh = blockIdx.y, split = blockIdx.x;
    int b = bh >> 3, h = bh & 7;
    int tid = threadIdx.x;
    size_t base = (size_t)b * NTOK * NQKV + h * 64;
    int t0 = split * CTOK;

    __shared__ float qls[64];
    __shared__ float sim[CTOK];
    __shared__ __attribute__((aligned(16))) unsigned short Vs[CTOK][64];
    __shared__ float red[256];
    __shared__ float Ms, Ss;

    if (tid < 64) qls[tid] = bf2f(qkv[base + tid]);    // q at t=0, sect 0

    // stage V (64 tokens x 64 dims): thread -> token tid>>2, quarter tid&3
    {
        int t = tid >> 2, q = tid & 3;
        size_t g = base + (size_t)(t0 + t) * NQKV + 1024 + q * 16;
        *(ushort8*)&Vs[t][q * 16]     = *(const ushort8*)(qkv + g);
        *(ushort8*)&Vs[t][q * 16 + 8] = *(const ushort8*)(qkv + g + 8);
    }
    __syncthreads();                                   // qls ready

    // sim: thread computes 16-dim partial dot for token tid>>2
    float pacc = 0.f;
    {
        int t = tid >> 2, q = tid & 3;
        size_t g = base + (size_t)(t0 + t) * NQKV + 512 + q * 16;
        bf16x8 k0 = *(const bf16x8*)(qkv + g);
        bf16x8 k1 = *(const bf16x8*)(qkv + g + 8);
#pragma unroll
        for (int e = 0; e < 8; e++) {
            pacc += qls[q * 16 + e]     * (float)k0[e];
            pacc += qls[q * 16 + 8 + e] * (float)k1[e];
        }
    }
    pacc += __shfl_xor(pacc, 1);
    pacc += __shfl_xor(pacc, 2);
    if ((tid & 3) == 0) {
        int t = tid >> 2;
        sim[t] = (t0 + t < NTOK) ? pacc : -1e30f;      // mask tail tokens
    }
    __syncthreads();

    if (tid < 64) {                                    // wave-parallel max+expsum
        float m = sim[tid];
#pragma unroll
        for (int off = 32; off > 0; off >>= 1) m = fmaxf(m, __shfl_xor(m, off));
        float p = __expf(sim[tid] - m);
        sim[tid] = p;
        float s = p;
#pragma unroll
        for (int off = 32; off > 0; off >>= 1) s += __shfl_xor(s, off);
        if (tid == 0) { Ms = m; Ss = s; }
    }
    __syncthreads();

    // PV: thread (grp=tid>>6, d=tid&63) accumulates 16 tokens
    int d = tid & 63, grp = tid >> 6;
    float acc = 0.f;
#pragma unroll
    for (int t = grp * 16; t < grp * 16 + 16; t++)
        acc += sim[t] * bf2f(Vs[t][d]);
    red[tid] = acc; __syncthreads();
    if (tid < 64) {
        float pv = red[tid] + red[tid + 64] + red[tid + 128] + red[tid + 192];
        float* pp = part + ((size_t)bh * CSPLIT + split) * 66;
        pp[2 + tid] = pv;
        if (tid == 0) { pp[0] = Ms; pp[1] = Ss; }
    }
}

// Merge 50 partials per (b,h) with online-softmax rescale; write CLS output.
__global__ __launch_bounds__(64) void cls_reduce(const float* __restrict__ part,
                                                 unsigned short* __restrict__ attn) {
    int bh = blockIdx.x, b = bh >> 3, h = bh & 7;
    int d = threadIdx.x;
    const float* pp = part + (size_t)bh * CSPLIT * 66;
    float M = -1e30f;
    for (int i = 0; i < CSPLIT; i++) M = fmaxf(M, pp[i * 66]);
    float S = 0.f, PV = 0.f;
    for (int i = 0; i < CSPLIT; i++) {
        float w = __expf(pp[i * 66] - M);
        S  += pp[i * 66 + 1] * w;
        PV += pp[i * 66 + 2 + d] * w;
    }
    attn[(size_t)(b * NTOK) * DIM + h * 64 + d] = f2bf(PV / S);
}

// ---------------- Time attention: one wave per (b,h,s) sequence ----------------
__global__ __launch_bounds__(256) void time_attn(const unsigned short* __restrict__ qkv,
                                                 unsigned short* __restrict__ attn) {
    int wave = threadIdx.x >> 6, lane = threadIdx.x & 63;
    int seq = blockIdx.x * 4 + wave;                   // 0 .. B_*H_*SP-1
    int bh = seq / SP, s = seq % SP;
    int b = bh >> 3, h = bh & 7;
    __shared__ __attribute__((aligned(16))) unsigned short Q[4][16][72];
    __shared__ __attribute__((aligned(16))) unsigned short Kt[4][17][72];
    __shared__ __attribute__((aligned(16))) unsigned short Vt[4][17][72];
    __shared__ float S[4][16][18];
    size_t base = (size_t)b * NTOK * NQKV + h * 64;

#pragma unroll
    for (int c = lane; c < 128; c += 64) {             // Q: 16 rows x 8 chunks
        int i = c >> 3, part = c & 7;
        size_t g = base + (size_t)(1 + i * SP + s) * NQKV + part * 8;
        *(ushort8*)&Q[wave][i][part * 8] = *(const ushort8*)(qkv + g);
    }
    for (int c = lane; c < 136; c += 64) {             // K,V: 17 rows x 8 chunks
        int j = c >> 3, part = c & 7;
        int t = (j == 0) ? 0 : (1 + (j - 1) * SP + s);
        size_t g = base + (size_t)t * NQKV + part * 8;
        *(ushort8*)&Kt[wave][j][part * 8] = *(const ushort8*)(qkv + g + 512);
        *(ushort8*)&Vt[wave][j][part * 8] = *(const ushort8*)(qkv + g + 1024);
    }
    __syncthreads();

    for (int p = lane; p < 272; p += 64) {             // S = Q K^T  (16x17)
        int i = p / 17, j = p - i * 17;
        float acc = 0.f;
#pragma unroll
        for (int c = 0; c < 8; c++) {
            bf16x8 qv = *(const bf16x8*)&Q[wave][i][c * 8];
            bf16x8 kv = *(const bf16x8*)&Kt[wave][j][c * 8];
#pragma unroll
            for (int e = 0; e < 8; e++) acc += (float)qv[e] * (float)kv[e];
        }
        S[wave][i][j] = acc;
    }
    __syncthreads();

    if (lane < 16) {                                   // row softmax (17 wide)
        int i = lane;
        float m = -1e30f;
#pragma unroll
        for (int j = 0; j < 17; j++) m = fmaxf(m, S[wave][i][j]);
        float sum = 0.f;
#pragma unroll
        for (int j = 0; j < 17; j++) {
            float p = __expf(S[wave][i][j] - m);
            S[wave][i][j] = p; sum += p;
        }
        float invs = 1.f / sum;
#pragma unroll
        for (int j = 0; j < 17; j++) S[wave][i][j] *= invs;
    }
    __syncthreads();

#pragma unroll
    for (int i = 0; i < 16; i++) {                     // O = P V, lane = dim
        float acc = 0.f;
#pragma unroll
        for (int j = 0; j < 17; j++)
            acc += S[wave][i][j] * bf2f(Vt[wave][j][lane]);
        attn[(size_t)(b * NTOK + 1 + i * SP + s) * DIM + h * 64 + lane] = f2bf(acc);
    }
}

// ---------------- launch ----------------

extern "C" void kernel_launch(void* const* d_in, const int* in_sizes, int n_in,
                              void* d_out, int out_size, void* d_ws, size_t ws_size,
                              hipStream_t stream) {
    (void)in_sizes; (void)n_in; (void)out_size; (void)ws_size;
    const float* x    = (const float*)d_in[0];
    const float* Wqkv = (const float*)d_in[1];
    const float* Wout = (const float*)d_in[2];
    const float* bout = (const float*)d_in[3];
    float* out = (float*)d_out;

    unsigned short* xb    = (unsigned short*)d_ws;                 // MPAD*512
    unsigned short* qkv   = xb    + (size_t)MPAD * DIM;            // MPAD*1536
    unsigned short* attn  = qkv   + (size_t)MPAD * NQKV;           // MPAD*512
    unsigned short* wqkvT = attn  + (size_t)MPAD * DIM;            // 1536*512
    unsigned short* woutT = wqkvT + (size_t)NQKV * DIM;            // 512*512
    float* clspart = (float*)xb;   // reuse xb region (dead after gemm<0>); 64*50*66 floats

    convert_pad_x<<<MPAD * DIM / 8 / 256, 256, 0, stream>>>(x, xb);
    transpose_w<<<dim3(NQKV / 32, DIM / 32), 256, 0, stream>>>(Wqkv, wqkvT, DIM, NQKV);
    transpose_w<<<dim3(DIM / 32, DIM / 32), 256, 0, stream>>>(Wout, woutT, DIM, DIM);
    zero_pad_attn<<<(MPAD - MREAL) * DIM / 8 / 256, 256, 0, stream>>>(attn);

    gemm_bt<0><<<dim3(MPAD / 128, NQKV / 128), 256, 0, stream>>>(
        xb, wqkvT, qkv, nullptr, nullptr, NQKV, DIM);

    cls_partial<<<dim3(CSPLIT, B_ * H_), 256, 0, stream>>>(qkv, clspart);
    cls_reduce<<<B_ * H_, 64, 0, stream>>>(clspart, attn);
    time_attn<<<(B_ * H_ * SP) / 4, 256, 0, stream>>>(qkv, attn);

    gemm_bt<1><<<dim3(MPAD / 128, DIM / 128), 256, 0, stream>>>(
        attn, woutT, nullptr, out, bout, DIM, DIM);
}

// Round 4
// 298.564 us; speedup vs baseline: 1.7351x; 1.0558x over previous
//
#include <hip/hip_runtime.h>
#include <hip/hip_bf16.h>

// Problem constants (fixed by setup_inputs)
#define B_    8
#define H_    8
#define DH_   64
#define FR    16
#define SP    196
#define NTOK  3137            // 1 + FR*SP
#define DIM   512
#define NQKV  1536
#define MREAL (B_ * NTOK)     // 25096
#define MPAD  25216           // 197 * 128

#define CSPLIT 50             // CLS split-K: 50 chunks of 64 tokens
#define CTOK   64

typedef __bf16 bf16x8 __attribute__((ext_vector_type(8)));
typedef float  f32x4  __attribute__((ext_vector_type(4)));
typedef unsigned short ushort8 __attribute__((ext_vector_type(8)));

__device__ __forceinline__ float bf2f(unsigned short u) {
    union { unsigned int i; float f; } x; x.i = ((unsigned int)u) << 16; return x.f;
}
__device__ __forceinline__ unsigned short f2bf(float f) {
    __hip_bfloat16 h = __float2bfloat16(f);
    union { __hip_bfloat16 h; unsigned short u; } x; x.h = h; return x.u;
}

// ---------------- prep kernels ----------------

// x (fp32, MREAL x 512) -> bf16 padded to MPAD rows (pad rows zero)
__global__ __launch_bounds__(256) void convert_pad_x(const float* __restrict__ x,
                                                     unsigned short* __restrict__ xb) {
    int idx = blockIdx.x * 256 + threadIdx.x;          // one 8-elem chunk each
    const int real8 = MREAL * DIM / 8;
    ushort8 o;
    if (idx < real8) {
        f32x4 a = *(const f32x4*)(x + (size_t)idx * 8);
        f32x4 b = *(const f32x4*)(x + (size_t)idx * 8 + 4);
        o[0] = f2bf(a[0]); o[1] = f2bf(a[1]); o[2] = f2bf(a[2]); o[3] = f2bf(a[3]);
        o[4] = f2bf(b[0]); o[5] = f2bf(b[1]); o[6] = f2bf(b[2]); o[7] = f2bf(b[3]);
    } else {
        o = (ushort8){0,0,0,0,0,0,0,0};
    }
    *(ushort8*)(xb + (size_t)idx * 8) = o;
}

// W (fp32, K x Nn) -> WT (bf16, Nn x K)   (B^T layout for the GEMM)
__global__ __launch_bounds__(256) void transpose_w(const float* __restrict__ W,
                                                   unsigned short* __restrict__ WT,
                                                   int K, int Nn) {
    __shared__ float tile[32][33];
    int n0 = blockIdx.x * 32, k0 = blockIdx.y * 32;
    int tx = threadIdx.x & 31, ty = threadIdx.x >> 5;   // ty 0..7
#pragma unroll
    for (int r = 0; r < 32; r += 8)
        tile[ty + r][tx] = W[(size_t)(k0 + ty + r) * Nn + n0 + tx];
    __syncthreads();
#pragma unroll
    for (int r = 0; r < 32; r += 8)
        WT[(size_t)(n0 + ty + r) * K + k0 + tx] = f2bf(tile[tx][ty + r]);
}

// zero the pad rows of the attention-output buffer (poisoned 0xAA each launch)
__global__ __launch_bounds__(256) void zero_pad_attn(unsigned short* __restrict__ attn) {
    int idx = blockIdx.x * 256 + threadIdx.x;           // (MPAD-MREAL)*512/8 chunks
    ushort8 z = (ushort8){0,0,0,0,0,0,0,0};
    *(ushort8*)(attn + (size_t)MREAL * DIM + (size_t)idx * 8) = z;
}

// ---------------- bf16 MFMA GEMM ----------------
// 128x128 tile, BK=32, double-buffered LDS (T3-minimum 2-phase), patch-swizzled
// 1D grid for A-panel L2/L3 locality.

__device__ __forceinline__ void gload_lds16(const unsigned short* g, unsigned short* l) {
    __builtin_amdgcn_global_load_lds((const __attribute__((address_space(1))) void*)g,
                                     (__attribute__((address_space(3))) void*)l, 16, 0, 0);
}

#define PATCH_M 16   // M-tiles per locality patch

// EPI 0: bf16 out, scale cols<DIM by 0.125 (q-scale).  EPI 1: fp32 out + bias, rows<MREAL.
template<int EPI>
__global__ __launch_bounds__(256)
void gemm_bt(const unsigned short* __restrict__ A, const unsigned short* __restrict__ Bt,
             unsigned short* __restrict__ Cb, float* __restrict__ Cf,
             const float* __restrict__ bias, int Nn, int K, int nM, int nN) {
    __shared__ __attribute__((aligned(16))) unsigned short As[2][128 * 32];
    __shared__ __attribute__((aligned(16))) unsigned short Bs[2][128 * 32];

    // patch-swizzle: groups of PATCH_M M-tiles sweep all N-tiles while the
    // A-patch (2 MB) + B panels stay hot in cache
    int id = blockIdx.x;
    int pid = id / (PATCH_M * nN);
    int rem = id - pid * (PATCH_M * nN);
    int m0 = pid * PATCH_M;
    int pm = min(PATCH_M, nM - m0);
    int tM = m0 + (rem % pm);
    int tN = rem / pm;

    int wave = threadIdx.x >> 6, lane = threadIdx.x & 63;
    int wm = wave >> 1, wn = wave & 1;                 // 2x2 waves, 64x64 each
    const int r15 = lane & 15, kq = (lane >> 4) * 8;
    f32x4 acc[4][4] = {};

    const unsigned short* Abase = A  + (size_t)(tM * 128) * K;
    const unsigned short* Bbase = Bt + (size_t)(tN * 128) * K;

    // staging geometry: chunk ce in [0,256): row = ce>>2, k-part = (ce&3)*8
    const int ce0 = wave * 64 + lane;          // phase-0 chunk for this thread
    const int ce1 = ce0 + 256;                 // phase-1 chunk (r=1)
    // (re-derived per call below to keep wave-uniform LDS base)

#define STAGE(buf, k0)                                                          \
    {                                                                           \
        _Pragma("unroll")                                                       \
        for (int r = 0; r < 2; ++r) {                                           \
            int chunk = (r * 4 + wave) * 64;                                    \
            int ce = chunk + lane;                                              \
            int row = ce >> 2, kp = (ce & 3) * 8;                               \
            gload_lds16(Abase + (size_t)row * K + (k0) + kp, &As[buf][chunk * 8]); \
            gload_lds16(Bbase + (size_t)row * K + (k0) + kp, &Bs[buf][chunk * 8]); \
        }                                                                       \
    }

    STAGE(0, 0)
    asm volatile("s_waitcnt vmcnt(0)" ::: "memory");
    __builtin_amdgcn_s_barrier();

    const int nK = K / 32;
    int cur = 0;
    for (int kt = 0; kt < nK; ++kt) {
        if (kt + 1 < nK) STAGE(cur ^ 1, (kt + 1) * 32)   // prefetch next K-tile
        bf16x8 af[4], bg[4];
#pragma unroll
        for (int m = 0; m < 4; m++)
            af[m] = *(const bf16x8*)&As[cur][(wm * 64 + m * 16 + r15) * 32 + kq];
#pragma unroll
        for (int nn2 = 0; nn2 < 4; nn2++)
            bg[nn2] = *(const bf16x8*)&Bs[cur][(wn * 64 + nn2 * 16 + r15) * 32 + kq];
        __builtin_amdgcn_s_setprio(1);
#pragma unroll
        for (int m = 0; m < 4; m++)
#pragma unroll
            for (int nn2 = 0; nn2 < 4; nn2++)
                acc[m][nn2] = __builtin_amdgcn_mfma_f32_16x16x32_bf16(af[m], bg[nn2], acc[m][nn2], 0, 0, 0);
        __builtin_amdgcn_s_setprio(0);
        asm volatile("s_waitcnt vmcnt(0)" ::: "memory");  // next tile landed
        __builtin_amdgcn_s_barrier();                     // all waves done reading cur
        cur ^= 1;
    }
#undef STAGE

    int rowBase = tM * 128 + wm * 64 + (lane >> 4) * 4;
    int colBase = tN * 128 + wn * 64 + r15;
#pragma unroll
    for (int m = 0; m < 4; m++) {
#pragma unroll
        for (int nn2 = 0; nn2 < 4; nn2++) {
            int col = colBase + nn2 * 16;
#pragma unroll
            for (int i = 0; i < 4; i++) {
                int row = rowBase + m * 16 + i;
                float v = acc[m][nn2][i];
                if constexpr (EPI == 0) {
                    if (col < DIM) v *= 0.125f;        // q scale = DH^-0.5
                    Cb[(size_t)row * Nn + col] = f2bf(v);
                } else {
                    if (row < MREAL) Cf[(size_t)row * Nn + col] = v + bias[col];
                }
            }
        }
    }
}

// ---------------- CLS attention: flash-style split-K ----------------
// qkv layout: [(b*NTOK + t) * 1536 + sect*512 + h*64 + d], q already scaled.
// Partial: block (split, bh) handles CTOK tokens -> (m, s, pv[64]) unnormalized.
__global__ __launch_bounds__(256) void cls_partial(const unsigned short* __restrict__ qkv,
                                                   float* __restrict__ part) {
    int bh = blockIdx.y, split = blockIdx.x;
    int b = bh >> 3, h = bh & 7;
    int tid = threadIdx.x;
    size_t base = (size_t)b * NTOK * NQKV + h * 64;
    int t0 = split * CTOK;

    __shared__ float qls[64];
    __shared__ float sim[CTOK];
    __shared__ __attribute__((aligned(16))) unsigned short Vs[CTOK][64];
    __shared__ float red[256];
    __shared__ float Ms, Ss;

    if (tid < 64) qls[tid] = bf2f(qkv[base + tid]);    // q at t=0, sect 0

    // stage V (64 tokens x 64 dims): thread -> token tid>>2, quarter tid&3
    {
        int t = tid >> 2, q = tid & 3;
        size_t g = base + (size_t)(t0 + t) * NQKV + 1024 + q * 16;
        *(ushort8*)&Vs[t][q * 16]     = *(const ushort8*)(qkv + g);
        *(ushort8*)&Vs[t][q * 16 + 8] = *(const ushort8*)(qkv + g + 8);
    }
    __syncthreads();                                   // qls ready

    // sim: thread computes 16-dim partial dot for token tid>>2
    float pacc = 0.f;
    {
        int t = tid >> 2, q = tid & 3;
        size_t g = base + (size_t)(t0 + t) * NQKV + 512 + q * 16;
        bf16x8 k0 = *(const bf16x8*)(qkv + g);
        bf16x8 k1 = *(const bf16x8*)(qkv + g + 8);
#pragma unroll
        for (int e = 0; e < 8; e++) {
            pacc += qls[q * 16 + e]     * (float)k0[e];
            pacc += qls[q * 16 + 8 + e] * (float)k1[e];
        }
    }
    pacc += __shfl_xor(pacc, 1);
    pacc += __shfl_xor(pacc, 2);
    if ((tid & 3) == 0) {
        int t = tid >> 2;
        sim[t] = (t0 + t < NTOK) ? pacc : -1e30f;      // mask tail tokens
    }
    __syncthreads();

    if (tid < 64) {                                    // wave-parallel max+expsum
        float m = sim[tid];
#pragma unroll
        for (int off = 32; off > 0; off >>= 1) m = fmaxf(m, __shfl_xor(m, off));
        float p = __expf(sim[tid] - m);
        sim[tid] = p;
        float s = p;
#pragma unroll
        for (int off = 32; off > 0; off >>= 1) s += __shfl_xor(s, off);
        if (tid == 0) { Ms = m; Ss = s; }
    }
    __syncthreads();

    // PV: thread (grp=tid>>6, d=tid&63) accumulates 16 tokens
    int d = tid & 63, grp = tid >> 6;
    float acc = 0.f;
#pragma unroll
    for (int t = grp * 16; t < grp * 16 + 16; t++)
        acc += sim[t] * bf2f(Vs[t][d]);
    red[tid] = acc; __syncthreads();
    if (tid < 64) {
        float pv = red[tid] + red[tid + 64] + red[tid + 128] + red[tid + 192];
        float* pp = part + ((size_t)bh * CSPLIT + split) * 66;
        pp[2 + tid] = pv;
        if (tid == 0) { pp[0] = Ms; pp[1] = Ss; }
    }
}

// Merge 50 partials per (b,h) with online-softmax rescale; write CLS output.
__global__ __launch_bounds__(64) void cls_reduce(const float* __restrict__ part,
                                                 unsigned short* __restrict__ attn) {
    int bh = blockIdx.x, b = bh >> 3, h = bh & 7;
    int d = threadIdx.x;
    const float* pp = part + (size_t)bh * CSPLIT * 66;
    float M = -1e30f;
    for (int i = 0; i < CSPLIT; i++) M = fmaxf(M, pp[i * 66]);
    float S = 0.f, PV = 0.f;
    for (int i = 0; i < CSPLIT; i++) {
        float w = __expf(pp[i * 66] - M);
        S  += pp[i * 66 + 1] * w;
        PV += pp[i * 66 + 2 + d] * w;
    }
    attn[(size_t)(b * NTOK) * DIM + h * 64 + d] = f2bf(PV / S);
}

// ---------------- Time attention: one wave per (b,h,s) sequence ----------------
__global__ __launch_bounds__(256) void time_attn(const unsigned short* __restrict__ qkv,
                                                 unsigned short* __restrict__ attn) {
    int wave = threadIdx.x >> 6, lane = threadIdx.x & 63;
    int seq = blockIdx.x * 4 + wave;                   // 0 .. B_*H_*SP-1
    int bh = seq / SP, s = seq % SP;
    int b = bh >> 3, h = bh & 7;
    __shared__ __attribute__((aligned(16))) unsigned short Q[4][16][72];
    __shared__ __attribute__((aligned(16))) unsigned short Kt[4][17][72];
    __shared__ __attribute__((aligned(16))) unsigned short Vt[4][17][72];
    __shared__ float S[4][16][18];
    size_t base = (size_t)b * NTOK * NQKV + h * 64;

#pragma unroll
    for (int c = lane; c < 128; c += 64) {             // Q: 16 rows x 8 chunks
        int i = c >> 3, part = c & 7;
        size_t g = base + (size_t)(1 + i * SP + s) * NQKV + part * 8;
        *(ushort8*)&Q[wave][i][part * 8] = *(const ushort8*)(qkv + g);
    }
    for (int c = lane; c < 136; c += 64) {             // K,V: 17 rows x 8 chunks
        int j = c >> 3, part = c & 7;
        int t = (j == 0) ? 0 : (1 + (j - 1) * SP + s);
        size_t g = base + (size_t)t * NQKV + part * 8;
        *(ushort8*)&Kt[wave][j][part * 8] = *(const ushort8*)(qkv + g + 512);
        *(ushort8*)&Vt[wave][j][part * 8] = *(const ushort8*)(qkv + g + 1024);
    }
    __syncthreads();

    for (int p = lane; p < 272; p += 64) {             // S = Q K^T  (16x17)
        int i = p / 17, j = p - i * 17;
        float acc = 0.f;
#pragma unroll
        for (int c = 0; c < 8; c++) {
            bf16x8 qv = *(const bf16x8*)&Q[wave][i][c * 8];
            bf16x8 kv = *(const bf16x8*)&Kt[wave][j][c * 8];
#pragma unroll
            for (int e = 0; e < 8; e++) acc += (float)qv[e] * (float)kv[e];
        }
        S[wave][i][j] = acc;
    }
    __syncthreads();

    if (lane < 16) {                                   // row softmax (17 wide)
        int i = lane;
        float m = -1e30f;
#pragma unroll
        for (int j = 0; j < 17; j++) m = fmaxf(m, S[wave][i][j]);
        float sum = 0.f;
#pragma unroll
        for (int j = 0; j < 17; j++) {
            float p = __expf(S[wave][i][j] - m);
            S[wave][i][j] = p; sum += p;
        }
        float invs = 1.f / sum;
#pragma unroll
        for (int j = 0; j < 17; j++) S[wave][i][j] *= invs;
    }
    __syncthreads();

#pragma unroll
    for (int i = 0; i < 16; i++) {                     // O = P V, lane = dim
        float acc = 0.f;
#pragma unroll
        for (int j = 0; j < 17; j++)
            acc += S[wave][i][j] * bf2f(Vt[wave][j][lane]);
        attn[(size_t)(b * NTOK + 1 + i * SP + s) * DIM + h * 64 + lane] = f2bf(acc);
    }
}

// ---------------- launch ----------------

extern "C" void kernel_launch(void* const* d_in, const int* in_sizes, int n_in,
                              void* d_out, int out_size, void* d_ws, size_t ws_size,
                              hipStream_t stream) {
    (void)in_sizes; (void)n_in; (void)out_size; (void)ws_size;
    const float* x    = (const float*)d_in[0];
    const float* Wqkv = (const float*)d_in[1];
    const float* Wout = (const float*)d_in[2];
    const float* bout = (const float*)d_in[3];
    float* out = (float*)d_out;

    unsigned short* xb    = (unsigned short*)d_ws;                 // MPAD*512
    unsigned short* qkv   = xb    + (size_t)MPAD * DIM;            // MPAD*1536
    unsigned short* attn  = qkv   + (size_t)MPAD * NQKV;           // MPAD*512
    unsigned short* wqkvT = attn  + (size_t)MPAD * DIM;            // 1536*512
    unsigned short* woutT = wqkvT + (size_t)NQKV * DIM;            // 512*512
    float* clspart = (float*)xb;   // reuse xb region (dead after gemm<0>); 64*50*66 floats

    convert_pad_x<<<MPAD * DIM / 8 / 256, 256, 0, stream>>>(x, xb);
    transpose_w<<<dim3(NQKV / 32, DIM / 32), 256, 0, stream>>>(Wqkv, wqkvT, DIM, NQKV);
    transpose_w<<<dim3(DIM / 32, DIM / 32), 256, 0, stream>>>(Wout, woutT, DIM, DIM);
    zero_pad_attn<<<(MPAD - MREAL) * DIM / 8 / 256, 256, 0, stream>>>(attn);

    const int nM = MPAD / 128;                 // 197
    gemm_bt<0><<<nM * (NQKV / 128), 256, 0, stream>>>(
        xb, wqkvT, qkv, nullptr, nullptr, NQKV, DIM, nM, NQKV / 128);

    cls_partial<<<dim3(CSPLIT, B_ * H_), 256, 0, stream>>>(qkv, clspart);
    cls_reduce<<<B_ * H_, 64, 0, stream>>>(clspart, attn);
    time_attn<<<(B_ * H_ * SP) / 4, 256, 0, stream>>>(qkv, attn);

    gemm_bt<1><<<nM * (DIM / 128), 256, 0, stream>>>(
        attn, woutT, nullptr, out, bout, DIM, DIM, nM, DIM / 128);
}

// Round 5
// 259.757 us; speedup vs baseline: 1.9943x; 1.1494x over previous
//
#include <hip/hip_runtime.h>
#include <hip/hip_bf16.h>

// Problem constants (fixed by setup_inputs)
#define B_    8
#define H_    8
#define DH_   64
#define FR    16
#define SP    196
#define NTOK  3137            // 1 + FR*SP
#define DIM   512
#define NQKV  1536
#define MREAL (B_ * NTOK)     // 25096
#define MPAD  25216           // 197 * 128

#define CSPLIT 50             // CLS split-K: 50 chunks of 64 tokens
#define CTOK   64

typedef __bf16 bf16x8 __attribute__((ext_vector_type(8)));
typedef float  f32x4  __attribute__((ext_vector_type(4)));
typedef unsigned short ushort8 __attribute__((ext_vector_type(8)));

__device__ __forceinline__ float bf2f(unsigned short u) {
    union { unsigned int i; float f; } x; x.i = ((unsigned int)u) << 16; return x.f;
}
__device__ __forceinline__ unsigned short f2bf(float f) {
    __hip_bfloat16 h = __float2bfloat16(f);
    union { __hip_bfloat16 h; unsigned short u; } x; x.h = h; return x.u;
}

// ---------------- prep kernels ----------------

// x (fp32, MREAL x 512) -> bf16 padded to MPAD rows (pad rows zero)
__global__ __launch_bounds__(256) void convert_pad_x(const float* __restrict__ x,
                                                     unsigned short* __restrict__ xb) {
    int idx = blockIdx.x * 256 + threadIdx.x;          // one 8-elem chunk each
    const int real8 = MREAL * DIM / 8;
    ushort8 o;
    if (idx < real8) {
        f32x4 a = *(const f32x4*)(x + (size_t)idx * 8);
        f32x4 b = *(const f32x4*)(x + (size_t)idx * 8 + 4);
        o[0] = f2bf(a[0]); o[1] = f2bf(a[1]); o[2] = f2bf(a[2]); o[3] = f2bf(a[3]);
        o[4] = f2bf(b[0]); o[5] = f2bf(b[1]); o[6] = f2bf(b[2]); o[7] = f2bf(b[3]);
    } else {
        o = (ushort8){0,0,0,0,0,0,0,0};
    }
    *(ushort8*)(xb + (size_t)idx * 8) = o;
}

// W (fp32, K x Nn) -> WT (bf16, Nn x K)   (B^T layout for the GEMM)
__global__ __launch_bounds__(256) void transpose_w(const float* __restrict__ W,
                                                   unsigned short* __restrict__ WT,
                                                   int K, int Nn) {
    __shared__ float tile[32][33];
    int n0 = blockIdx.x * 32, k0 = blockIdx.y * 32;
    int tx = threadIdx.x & 31, ty = threadIdx.x >> 5;   // ty 0..7
#pragma unroll
    for (int r = 0; r < 32; r += 8)
        tile[ty + r][tx] = W[(size_t)(k0 + ty + r) * Nn + n0 + tx];
    __syncthreads();
#pragma unroll
    for (int r = 0; r < 32; r += 8)
        WT[(size_t)(n0 + ty + r) * K + k0 + tx] = f2bf(tile[tx][ty + r]);
}

// zero the pad rows of the attention-output buffer (poisoned 0xAA each launch)
__global__ __launch_bounds__(256) void zero_pad_attn(unsigned short* __restrict__ attn) {
    int idx = blockIdx.x * 256 + threadIdx.x;           // (MPAD-MREAL)*512/8 chunks
    ushort8 z = (ushort8){0,0,0,0,0,0,0,0};
    *(ushort8*)(attn + (size_t)MREAL * DIM + (size_t)idx * 8) = z;
}

// ---------------- bf16 MFMA GEMM ----------------
// 128x128 tile, BK=32, double-buffered LDS (2-phase), patch-swizzled 1D grid.

__device__ __forceinline__ void gload_lds16(const unsigned short* g, unsigned short* l) {
    __builtin_amdgcn_global_load_lds((const __attribute__((address_space(1))) void*)g,
                                     (__attribute__((address_space(3))) void*)l, 16, 0, 0);
}

#define PATCH_M 16   // M-tiles per locality patch

// EPI 0: bf16 out, scale cols<DIM by 0.125 (q-scale).  EPI 1: fp32 out + bias, rows<MREAL.
template<int EPI>
__global__ __launch_bounds__(256)
void gemm_bt(const unsigned short* __restrict__ A, const unsigned short* __restrict__ Bt,
             unsigned short* __restrict__ Cb, float* __restrict__ Cf,
             const float* __restrict__ bias, int Nn, int K, int nM, int nN) {
    __shared__ __attribute__((aligned(16))) unsigned short As[2][128 * 32];
    __shared__ __attribute__((aligned(16))) unsigned short Bs[2][128 * 32];

    int id = blockIdx.x;
    int pid = id / (PATCH_M * nN);
    int rem = id - pid * (PATCH_M * nN);
    int m0 = pid * PATCH_M;
    int pm = min(PATCH_M, nM - m0);
    int tM = m0 + (rem % pm);
    int tN = rem / pm;

    int wave = threadIdx.x >> 6, lane = threadIdx.x & 63;
    int wm = wave >> 1, wn = wave & 1;                 // 2x2 waves, 64x64 each
    const int r15 = lane & 15, kq = (lane >> 4) * 8;
    f32x4 acc[4][4] = {};

    const unsigned short* Abase = A  + (size_t)(tM * 128) * K;
    const unsigned short* Bbase = Bt + (size_t)(tN * 128) * K;

#define STAGE(buf, k0)                                                          \
    {                                                                           \
        _Pragma("unroll")                                                       \
        for (int r = 0; r < 2; ++r) {                                           \
            int chunk = (r * 4 + wave) * 64;                                    \
            int ce = chunk + lane;                                              \
            int row = ce >> 2, kp = (ce & 3) * 8;                               \
            gload_lds16(Abase + (size_t)row * K + (k0) + kp, &As[buf][chunk * 8]); \
            gload_lds16(Bbase + (size_t)row * K + (k0) + kp, &Bs[buf][chunk * 8]); \
        }                                                                       \
    }

    STAGE(0, 0)
    asm volatile("s_waitcnt vmcnt(0)" ::: "memory");
    __builtin_amdgcn_s_barrier();

    const int nK = K / 32;
    int cur = 0;
    for (int kt = 0; kt < nK; ++kt) {
        if (kt + 1 < nK) STAGE(cur ^ 1, (kt + 1) * 32)   // prefetch next K-tile
        bf16x8 af[4], bg[4];
#pragma unroll
        for (int m = 0; m < 4; m++)
            af[m] = *(const bf16x8*)&As[cur][(wm * 64 + m * 16 + r15) * 32 + kq];
#pragma unroll
        for (int nn2 = 0; nn2 < 4; nn2++)
            bg[nn2] = *(const bf16x8*)&Bs[cur][(wn * 64 + nn2 * 16 + r15) * 32 + kq];
        __builtin_amdgcn_s_setprio(1);
#pragma unroll
        for (int m = 0; m < 4; m++)
#pragma unroll
            for (int nn2 = 0; nn2 < 4; nn2++)
                acc[m][nn2] = __builtin_amdgcn_mfma_f32_16x16x32_bf16(af[m], bg[nn2], acc[m][nn2], 0, 0, 0);
        __builtin_amdgcn_s_setprio(0);
        asm volatile("s_waitcnt vmcnt(0)" ::: "memory");  // next tile landed
        __builtin_amdgcn_s_barrier();                     // all waves done reading cur
        cur ^= 1;
    }
#undef STAGE

    int rowBase = tM * 128 + wm * 64 + (lane >> 4) * 4;
    int colBase = tN * 128 + wn * 64 + r15;
#pragma unroll
    for (int m = 0; m < 4; m++) {
#pragma unroll
        for (int nn2 = 0; nn2 < 4; nn2++) {
            int col = colBase + nn2 * 16;
#pragma unroll
            for (int i = 0; i < 4; i++) {
                int row = rowBase + m * 16 + i;
                float v = acc[m][nn2][i];
                if constexpr (EPI == 0) {
                    if (col < DIM) v *= 0.125f;        // q scale = DH^-0.5
                    Cb[(size_t)row * Nn + col] = f2bf(v);
                } else {
                    if (row < MREAL) Cf[(size_t)row * Nn + col] = v + bias[col];
                }
            }
        }
    }
}

// ---------------- CLS attention: flash-style split-K ----------------
__global__ __launch_bounds__(256) void cls_partial(const unsigned short* __restrict__ qkv,
                                                   float* __restrict__ part) {
    int bh = blockIdx.y, split = blockIdx.x;
    int b = bh >> 3, h = bh & 7;
    int tid = threadIdx.x;
    size_t base = (size_t)b * NTOK * NQKV + h * 64;
    int t0 = split * CTOK;

    __shared__ float qls[64];
    __shared__ float sim[CTOK];
    __shared__ __attribute__((aligned(16))) unsigned short Vs[CTOK][64];
    __shared__ float red[256];
    __shared__ float Ms, Ss;

    if (tid < 64) qls[tid] = bf2f(qkv[base + tid]);    // q at t=0, sect 0

    {
        int t = tid >> 2, q = tid & 3;
        size_t g = base + (size_t)(t0 + t) * NQKV + 1024 + q * 16;
        *(ushort8*)&Vs[t][q * 16]     = *(const ushort8*)(qkv + g);
        *(ushort8*)&Vs[t][q * 16 + 8] = *(const ushort8*)(qkv + g + 8);
    }
    __syncthreads();

    float pacc = 0.f;
    {
        int t = tid >> 2, q = tid & 3;
        size_t g = base + (size_t)(t0 + t) * NQKV + 512 + q * 16;
        bf16x8 k0 = *(const bf16x8*)(qkv + g);
        bf16x8 k1 = *(const bf16x8*)(qkv + g + 8);
#pragma unroll
        for (int e = 0; e < 8; e++) {
            pacc += qls[q * 16 + e]     * (float)k0[e];
            pacc += qls[q * 16 + 8 + e] * (float)k1[e];
        }
    }
    pacc += __shfl_xor(pacc, 1);
    pacc += __shfl_xor(pacc, 2);
    if ((tid & 3) == 0) {
        int t = tid >> 2;
        sim[t] = (t0 + t < NTOK) ? pacc : -1e30f;
    }
    __syncthreads();

    if (tid < 64) {
        float m = sim[tid];
#pragma unroll
        for (int off = 32; off > 0; off >>= 1) m = fmaxf(m, __shfl_xor(m, off));
        float p = __expf(sim[tid] - m);
        sim[tid] = p;
        float s = p;
#pragma unroll
        for (int off = 32; off > 0; off >>= 1) s += __shfl_xor(s, off);
        if (tid == 0) { Ms = m; Ss = s; }
    }
    __syncthreads();

    int d = tid & 63, grp = tid >> 6;
    float acc = 0.f;
#pragma unroll
    for (int t = grp * 16; t < grp * 16 + 16; t++)
        acc += sim[t] * bf2f(Vs[t][d]);
    red[tid] = acc; __syncthreads();
    if (tid < 64) {
        float pv = red[tid] + red[tid + 64] + red[tid + 128] + red[tid + 192];
        float* pp = part + ((size_t)bh * CSPLIT + split) * 66;
        pp[2 + tid] = pv;
        if (tid == 0) { pp[0] = Ms; pp[1] = Ss; }
    }
}

__global__ __launch_bounds__(64) void cls_reduce(const float* __restrict__ part,
                                                 unsigned short* __restrict__ attn) {
    int bh = blockIdx.x, b = bh >> 3, h = bh & 7;
    int d = threadIdx.x;
    const float* pp = part + (size_t)bh * CSPLIT * 66;
    float M = -1e30f;
    for (int i = 0; i < CSPLIT; i++) M = fmaxf(M, pp[i * 66]);
    float S = 0.f, PV = 0.f;
    for (int i = 0; i < CSPLIT; i++) {
        float w = __expf(pp[i * 66] - M);
        S  += pp[i * 66 + 1] * w;
        PV += pp[i * 66 + 2 + d] * w;
    }
    attn[(size_t)(b * NTOK) * DIM + h * 64 + d] = f2bf(PV / S);
}

// ---------------- Time attention: MFMA, one wave per (b,h,s) sequence ----------------
// Per-wave LDS slice (shorts): Q [16][88], K [17][88] (B-frag tile1 reads rows 16-31,
// overflowing into the Vt region - finite garbage, masked via P zeros / softmax mask),
// Vt [64][40] (V transposed, dim-major; cols 17-31 zeroed), P [16][40] bf16.
#define QOFF 0
#define KOFF 1408
#define VOFF 2904
#define POFF 5464
#define WSLICE 6112   // 12224 B per wave; x4 waves = 48.9 KB -> 3 blocks/CU

__global__ __launch_bounds__(256) void time_attn(const unsigned short* __restrict__ qkv,
                                                 unsigned short* __restrict__ attn) {
    __shared__ __attribute__((aligned(16))) unsigned short lds[4][WSLICE];
    int wave = threadIdx.x >> 6, lane = threadIdx.x & 63;
    unsigned short* W = lds[wave];
    int seq = blockIdx.x * 4 + wave;                   // 0 .. B_*H_*SP-1
    int bh = seq / SP, s = seq - bh * SP;
    int b = bh >> 3, h = bh & 7;
    size_t base = (size_t)b * NTOK * NQKV + h * 64;
    const int r15 = lane & 15, q4 = lane >> 4, kq = q4 * 8;

    // zero Vt pad cols 16..31 (col 16 overwritten by scatter below, same-wave in-order)
    {
        ushort8 z = (ushort8){0,0,0,0,0,0,0,0};
#pragma unroll
        for (int r = 0; r < 2; ++r) {
            int c = r * 64 + lane;                     // 128 chunks: row d=c>>1, half c&1
            *(ushort8*)&W[VOFF + (c >> 1) * 40 + 16 + (c & 1) * 8] = z;
        }
    }
    // Q: 16 rows x 8 parts
#pragma unroll
    for (int r = 0; r < 2; ++r) {
        int c = r * 64 + lane;
        int i = c >> 3, part = c & 7;
        *(ushort8*)&W[QOFF + i * 88 + part * 8] =
            *(const ushort8*)(qkv + base + (size_t)(1 + i * SP + s) * NQKV + part * 8);
    }
    // K (row-major) + V (transposed scatter): 17 rows x 8 parts = 136 chunks
    for (int c = lane; c < 136; c += 64) {
        int j = c >> 3, part = c & 7;
        int t = (j == 0) ? 0 : (1 + (j - 1) * SP + s);
        const unsigned short* g = qkv + base + (size_t)t * NQKV + part * 8;
        *(ushort8*)&W[KOFF + j * 88 + part * 8] = *(const ushort8*)(g + 512);
        ushort8 v = *(const ushort8*)(g + 1024);
#pragma unroll
        for (int e = 0; e < 8; e++)
            W[VOFF + (part * 8 + e) * 40 + j] = v[e];  // Vt[d][j]
    }
    __syncthreads();

    // S = Q K^T : 16x32 (cols 0..16 valid), 4 MFMA
    f32x4 sc0 = {0.f, 0.f, 0.f, 0.f}, sc1 = {0.f, 0.f, 0.f, 0.f};
#pragma unroll
    for (int ks = 0; ks < 2; ++ks) {
        bf16x8 aq = *(const bf16x8*)&W[QOFF + r15 * 88 + ks * 32 + kq];
        bf16x8 b0 = *(const bf16x8*)&W[KOFF + r15 * 88 + ks * 32 + kq];
        bf16x8 b1 = *(const bf16x8*)&W[KOFF + (16 + r15) * 88 + ks * 32 + kq];
        sc0 = __builtin_amdgcn_mfma_f32_16x16x32_bf16(aq, b0, sc0, 0, 0, 0);
        sc1 = __builtin_amdgcn_mfma_f32_16x16x32_bf16(aq, b1, sc1, 0, 0, 0);
    }

    // softmax over j=0..16; C layout: col=lane&15, row=(lane>>4)*4+i
#pragma unroll
    for (int i = 0; i < 4; ++i) {
        float t0 = sc0[i];
        float t1 = sc1[i];
        float t1v = (r15 == 0) ? t1 : -1e30f;
        float m = fmaxf(t0, t1v);
        m = fmaxf(m, __shfl_xor(m, 1));
        m = fmaxf(m, __shfl_xor(m, 2));
        m = fmaxf(m, __shfl_xor(m, 4));
        m = fmaxf(m, __shfl_xor(m, 8));
        float p0 = __expf(t0 - m);
        float p1 = (r15 == 0) ? __expf(t1 - m) : 0.f;
        float sum = p0 + p1;
        sum += __shfl_xor(sum, 1);
        sum += __shfl_xor(sum, 2);
        sum += __shfl_xor(sum, 4);
        sum += __shfl_xor(sum, 8);
        float inv = 1.f / sum;
        int f = q4 * 4 + i;
        W[POFF + f * 40 + r15]      = f2bf(p0 * inv);
        W[POFF + f * 40 + 16 + r15] = f2bf(p1 * inv);  // zero for pad keys 17..31
    }
    __syncthreads();

    // O = P V : 16x64, 4 MFMA (contraction over 32 padded keys; P zeros mask pads)
    bf16x8 ap = *(const bf16x8*)&W[POFF + r15 * 40 + kq];
    f32x4 o[4];
#pragma unroll
    for (int t = 0; t < 4; ++t) {
        f32x4 z = {0.f, 0.f, 0.f, 0.f};
        bf16x8 bv = *(const bf16x8*)&W[VOFF + (t * 16 + r15) * 40 + kq];
        o[t] = __builtin_amdgcn_mfma_f32_16x16x32_bf16(ap, bv, z, 0, 0, 0);
    }

    // write: row=(lane>>4)*4+i -> frame f; col=t*16+(lane&15) -> dim
#pragma unroll
    for (int t = 0; t < 4; ++t)
#pragma unroll
        for (int i = 0; i < 4; ++i) {
            int f = q4 * 4 + i;
            attn[(size_t)(b * NTOK + 1 + f * SP + s) * DIM + h * 64 + t * 16 + r15] =
                f2bf(o[t][i]);
        }
}

// ---------------- launch ----------------

extern "C" void kernel_launch(void* const* d_in, const int* in_sizes, int n_in,
                              void* d_out, int out_size, void* d_ws, size_t ws_size,
                              hipStream_t stream) {
    (void)in_sizes; (void)n_in; (void)out_size; (void)ws_size;
    const float* x    = (const float*)d_in[0];
    const float* Wqkv = (const float*)d_in[1];
    const float* Wout = (const float*)d_in[2];
    const float* bout = (const float*)d_in[3];
    float* out = (float*)d_out;

    unsigned short* xb    = (unsigned short*)d_ws;                 // MPAD*512
    unsigned short* qkv   = xb    + (size_t)MPAD * DIM;            // MPAD*1536
    unsigned short* attn  = qkv   + (size_t)MPAD * NQKV;           // MPAD*512
    unsigned short* wqkvT = attn  + (size_t)MPAD * DIM;            // 1536*512
    unsigned short* woutT = wqkvT + (size_t)NQKV * DIM;            // 512*512
    float* clspart = (float*)xb;   // reuse xb region (dead after gemm<0>)

    convert_pad_x<<<MPAD * DIM / 8 / 256, 256, 0, stream>>>(x, xb);
    transpose_w<<<dim3(NQKV / 32, DIM / 32), 256, 0, stream>>>(Wqkv, wqkvT, DIM, NQKV);
    transpose_w<<<dim3(DIM / 32, DIM / 32), 256, 0, stream>>>(Wout, woutT, DIM, DIM);
    zero_pad_attn<<<(MPAD - MREAL) * DIM / 8 / 256, 256, 0, stream>>>(attn);

    const int nM = MPAD / 128;                 // 197
    gemm_bt<0><<<nM * (NQKV / 128), 256, 0, stream>>>(
        xb, wqkvT, qkv, nullptr, nullptr, NQKV, DIM, nM, NQKV / 128);

    cls_partial<<<dim3(CSPLIT, B_ * H_), 256, 0, stream>>>(qkv, clspart);
    cls_reduce<<<B_ * H_, 64, 0, stream>>>(clspart, attn);
    time_attn<<<(B_ * H_ * SP) / 4, 256, 0, stream>>>(qkv, attn);

    gemm_bt<1><<<nM * (DIM / 128), 256, 0, stream>>>(
        attn, woutT, nullptr, out, bout, DIM, DIM, nM, DIM / 128);
}